// Round 2
// baseline (95.919 us; speedup 1.0000x reference)
//
#include <hip/hip_runtime.h>

// NestedFormula: DEPTH=4, V=4, B=131072.
// Level node counts: n1=125, n2=25, n3=5, n4=1; lam0 has 125 entries.
// Depth-first evaluation, 1 thread per batch element.
// Params (~5.5KB) are wave-uniform -> scalar loads after full unroll.

#define VV 4

__global__ __launch_bounds__(256) void nested_formula_kernel(
    const float4* __restrict__ x,      // (B, 4) as float4
    const float*  __restrict__ lam0,   // (125,)
    const float*  __restrict__ lam1,   // (125,4)
    const float*  __restrict__ pow1,   // (125,4)
    const float*  __restrict__ lam2,   // (25,4)
    const float*  __restrict__ pow2,   // (25,4)
    const float*  __restrict__ lam3,   // (5,4)
    const float*  __restrict__ pow3,   // (5,4)
    const float*  __restrict__ lam4,   // (1,4)
    const float*  __restrict__ pow4,   // (1,4)
    float* __restrict__ out,           // (B,)
    int B)
{
    int b = blockIdx.x * blockDim.x + threadIdx.x;
    if (b >= B) return;

    float4 xv = x[b];
    float lx[VV] = { log2f(xv.x), log2f(xv.y), log2f(xv.z), log2f(xv.w) };

    float acc4 = 0.f, last4 = 0.f;
#pragma unroll
    for (int c3 = 0; c3 < VV + 1; ++c3) {
        // depth-3 node index n3 = c3 (children of the single depth-4 node)
        float acc3 = 0.f, last3 = 0.f;
#pragma unroll
        for (int c2 = 0; c2 < VV + 1; ++c2) {
            int n2 = c3 * (VV + 1) + c2;          // depth-2 node index, 0..24
            float acc2 = 0.f, last2 = 0.f;
#pragma unroll
            for (int c1 = 0; c1 < VV + 1; ++c1) {
                int n1 = n2 * (VV + 1) + c1;      // depth-1 node index, 0..124
                // f1 = sum_v lam1[n1,v] * x_v^pow1[n1,v] + lam0[n1]
                float f1 = lam0[n1];
#pragma unroll
                for (int v = 0; v < VV; ++v) {
                    float xp = exp2f(pow1[n1 * VV + v] * lx[v]);
                    f1 = fmaf(lam1[n1 * VV + v], xp, f1);
                }
                if (c1 < VV) {
                    float xp = exp2f(pow2[n2 * VV + c1] * lx[c1]);
                    acc2 = fmaf(lam2[n2 * VV + c1] * xp, f1, acc2);
                } else {
                    last2 = f1;
                }
            }
            float f2 = acc2 + last2;
            if (c2 < VV) {
                float xp = exp2f(pow3[c3 * VV + c2] * lx[c2]);
                acc3 = fmaf(lam3[c3 * VV + c2] * xp, f2, acc3);
            } else {
                last3 = f2;
            }
        }
        float f3 = acc3 + last3;
        if (c3 < VV) {
            float xp = exp2f(pow4[c3] * lx[c3]);
            acc4 = fmaf(lam4[c3] * xp, f3, acc4);
        } else {
            last4 = f3;
        }
    }
    out[b] = acc4 + last4;
}

extern "C" void kernel_launch(void* const* d_in, const int* in_sizes, int n_in,
                              void* d_out, int out_size, void* d_ws, size_t ws_size,
                              hipStream_t stream) {
    const float4* x    = (const float4*)d_in[0];
    const float*  lam0 = (const float*)d_in[1];
    const float*  lam1 = (const float*)d_in[2];
    const float*  pow1 = (const float*)d_in[3];
    const float*  lam2 = (const float*)d_in[4];
    const float*  pow2 = (const float*)d_in[5];
    const float*  lam3 = (const float*)d_in[6];
    const float*  pow3 = (const float*)d_in[7];
    const float*  lam4 = (const float*)d_in[8];
    const float*  pow4 = (const float*)d_in[9];
    float* out = (float*)d_out;

    int B = in_sizes[0] / 4;  // x is (B, 4)
    int block = 256;
    int grid = (B + block - 1) / block;
    nested_formula_kernel<<<grid, block, 0, stream>>>(
        x, lam0, lam1, pow1, lam2, pow2, lam3, pow3, lam4, pow4, out, B);
}